// Round 16
// baseline (58.949 us; speedup 1.0000x reference)
//
#include <hip/hip_runtime.h>
#include <math.h>

#define BLOCK 256
#define QPT 8     // queries per thread
#define CS  256   // refs per chunk (8-bit local idx in masked low key bits)

typedef unsigned long long u64;

// Setup: pack refs into uniform-loadable uint4(-2x,-2y,-2z, ||r||^2+64),
// init part sentinels, zero out. One dispatch, no memsets.
// packed: [B*N dir0 refs = dst][B*M dir1 refs = src]; part: [B*M][B*N].
__global__ void chamfer_setup_kernel(const float* __restrict__ pc_src,
                                     const float* __restrict__ pc_dst,
                                     uint4* __restrict__ packed,
                                     u64* __restrict__ part,
                                     float* __restrict__ out,
                                     int M, int N, int B) {
    const int t = blockIdx.x * BLOCK + threadIdx.x;
    const int TOT0 = B * N;
    const int dir = (t >= TOT0);
    const int NR = dir ? M : N;
    const float* pc = dir ? pc_src : pc_dst;
    const int tt = dir ? t - TOT0 : t;
    const int b = tt / NR, i = tt - b * NR;
    const float* rb = pc + (size_t)b * 3 * NR;
    const float rx = rb[i], ry = rb[NR + i], rz = rb[2 * NR + i];
    uint4 v;
    v.x = __float_as_uint(-2.0f * rx);
    v.y = __float_as_uint(-2.0f * ry);
    v.z = __float_as_uint(-2.0f * rz);
    v.w = __float_as_uint(fmaf(rx, rx, fmaf(ry, ry, rz * rz)) + 64.0f);
    packed[t] = v;
    part[t] = ~0ull;                 // same element count B*(M+N)
    if (t == 0) *out = 0.0f;
}

// R13 structure (fastest of the 7-variant plateau, absmax 0.0 verified),
// single delta: CS 64 -> 256. Mechanism: each block pays ~24 query loads +
// QPT u64 atomics around the body; at CS=64 that prologue/epilogue wraps only
// 64 iterations — CS=256 amortizes it 4x and cuts atomicMin traffic 4x.
// Hot loop/pair: 3 v_fma + v_and_or + v_min = 5 slots, refs via wave-uniform
// loads. e = d^2 + 64 - ||q||^2 > 0 so u32 order == float order; low 8 bits
// carry local ref idx (selection granularity ~2e-3 in d^2; the reduce kernel
// recomputes the winning distance EXACTLY from raw f32 coords). Epilogue:
// device-scope atomicMin(u64) per (query, chunk), key =
// (masked_e << 32) | global_idx — commutative/idempotent => deterministic;
// ties pick lowest global index (jnp.argmin first-occurrence).
__global__ __launch_bounds__(BLOCK, 8)
void chamfer_min_kernel(const uint4* __restrict__ packed,
                        const float* __restrict__ pc_src,
                        const float* __restrict__ pc_dst,
                        u64* __restrict__ part,
                        int M, int N, int B, int Zc0) {
    const int b = blockIdx.y;
    const int z = blockIdx.z;
    const int dir = (z >= Zc0) ? 1 : 0;
    const int chunk = dir ? (z - Zc0) : z;

    const int NQ = dir ? N : M;
    const float* pcq = dir ? pc_dst : pc_src;
    const uint4* rp = packed
        + (dir ? (size_t)B * N + (size_t)b * M : (size_t)b * N)
        + (size_t)chunk * CS;
    u64* pp = part + (dir ? (size_t)B * M : (size_t)0) + (size_t)b * NQ;

    const int tid = threadIdx.x;
    const int q0 = blockIdx.x * (BLOCK * QPT) + tid;
    const float* qb = pcq + (size_t)b * 3 * NQ;

    float qx[QPT], qy[QPT], qz[QPT];
    unsigned kmin[QPT];
#pragma unroll
    for (int j = 0; j < QPT; ++j) {
        const int q = q0 + j * BLOCK;
        qx[j] = qb[q];
        qy[j] = qb[NQ + q];
        qz[j] = qb[2 * NQ + q];
        kmin[j] = 0xFFFFFFFFu;
    }

#pragma unroll 8
    for (int i = 0; i < CS; ++i) {
        const uint4 rv = rp[i];          // wave-uniform ref load
        const float rx = __uint_as_float(rv.x);
        const float ry = __uint_as_float(rv.y);
        const float rz = __uint_as_float(rv.z);
        const float wv = __uint_as_float(rv.w);
        const unsigned idx = (unsigned)i;
#pragma unroll
        for (int j = 0; j < QPT; ++j) {
            const float e = fmaf(qx[j], rx, fmaf(qy[j], ry, fmaf(qz[j], rz, wv)));
            const unsigned key = (__float_as_uint(e) & ~255u) | idx;
            kmin[j] = key < kmin[j] ? key : kmin[j];
        }
    }

    const unsigned n0 = (unsigned)(chunk * CS);
#pragma unroll
    for (int j = 0; j < QPT; ++j) {
        const int q = q0 + j * BLOCK;
        const u64 key = ((u64)(kmin[j] & ~255u) << 32) | (u64)(n0 + (kmin[j] & 255u));
        atomicMin(&pp[q], key);
    }
}

// Epilogue: one thread per query (both directions concatenated in part).
// Low 32 bits of key64 = global argmin ref index; recompute the winning
// distance EXACTLY from raw f32 coords, weight by sigma, block-reduce,
// one atomicAdd per block.
__global__ void chamfer_reduce_kernel(const float* __restrict__ pc_src,
                                      const float* __restrict__ pc_dst,
                                      const float* __restrict__ sig_src,
                                      const float* __restrict__ sig_dst,
                                      const u64* __restrict__ part,
                                      float* __restrict__ out,
                                      int M, int N, int B) {
    __shared__ float red[BLOCK];
    const int TT = blockIdx.x * BLOCK + threadIdx.x;
    const int dir = (TT >= B * M);           // uniform per block (B*M % 256 == 0)
    const int t = dir ? TT - B * M : TT;     // t = b*NQ + q

    const int NQ = dir ? N : M;
    const int NR = dir ? M : N;
    const float* pcq  = dir ? pc_dst : pc_src;
    const float* pcr  = dir ? pc_src : pc_dst;
    const float* sigq = dir ? sig_dst : sig_src;
    const float* sigr = dir ? sig_src : sig_dst;
    const float scale = 1.0f / (float)(B * NQ);

    const int b = t / NQ;
    const int q = t - b * NQ;

    const int gidx = (int)(unsigned)part[TT];

    const float* qbase = pcq + (size_t)b * 3 * NQ;
    const float* rbase = pcr + (size_t)b * 3 * NR;
    const float dx = qbase[q]          - rbase[gidx];
    const float dy = qbase[NQ + q]     - rbase[NR + gidx];
    const float dz = qbase[2 * NQ + q] - rbase[2 * NR + gidx];
    const float dist = sqrtf(fmaf(dx, dx, fmaf(dy, dy, dz * dz)));

    const float s = 0.5f * (sigq[t] + sigr[(size_t)b * NR + gidx]);
    red[threadIdx.x] = dist * s * scale;
    __syncthreads();

    for (int w = BLOCK / 2; w > 0; w >>= 1) {
        if (threadIdx.x < w) red[threadIdx.x] += red[threadIdx.x + w];
        __syncthreads();
    }
    if (threadIdx.x == 0) atomicAdd(out, red[0]);
}

extern "C" void kernel_launch(void* const* d_in, const int* in_sizes, int n_in,
                              void* d_out, int out_size, void* d_ws, size_t ws_size,
                              hipStream_t stream) {
    const float* pc_src  = (const float*)d_in[0];   // [B,3,M]
    const float* pc_dst  = (const float*)d_in[1];   // [B,3,N]
    const float* sig_src = (const float*)d_in[2];   // [B,M]
    const float* sig_dst = (const float*)d_in[3];   // [B,N]
    float* out = (float*)d_out;

    const int B = 8;
    const int M = in_sizes[2] / B;   // 4096
    const int N = in_sizes[3] / B;   // 4096

    // d_ws layout: part (B*(M+N) u64 = 512 KiB) | packed (B*(M+N) uint4 = 1 MiB)
    u64* part = (u64*)d_ws;
    uint4* packed = (uint4*)((char*)d_ws + (size_t)B * (M + N) * sizeof(u64));

    const int TOT = B * (M + N);     // 65536

    {   // setup: pack refs + sentinels + zero out (no memsets)
        chamfer_setup_kernel<<<TOT / BLOCK, BLOCK, 0, stream>>>(
            pc_src, pc_dst, packed, part, out, M, N, B);
    }
    {   // min-scan, both directions: grid (2, 8, 32) = 512 blocks
        const int Zc0 = N / CS;
        const int Zc1 = M / CS;
        dim3 grid(M / (BLOCK * QPT), B, Zc0 + Zc1);
        chamfer_min_kernel<<<grid, BLOCK, 0, stream>>>(
            packed, pc_src, pc_dst, part, M, N, B, Zc0);
    }
    {   // epilogue over all queries of both directions
        dim3 rgrid(TOT / BLOCK);
        chamfer_reduce_kernel<<<rgrid, BLOCK, 0, stream>>>(
            pc_src, pc_dst, sig_src, sig_dst, part, out, M, N, B);
    }
}